// Round 1
// baseline (5380.650 us; speedup 1.0000x reference)
//
#include <hip/hip_runtime.h>
#include <hip/hip_bf16.h>

// Problem constants
#define DD 2048
#define TT 512
#define NBLK 64           // recurrence workgroups
#define HF_SLOT 32768     // elements per h fragment slot (16 x 2048)
#define KT 64             // K tiles of 32 (DD/32)

typedef __attribute__((ext_vector_type(4))) float  f32x4;
typedef __attribute__((ext_vector_type(8))) short  bf16x8;
typedef __attribute__((ext_vector_type(8))) unsigned short u16x8;
typedef unsigned short ushort_t;

__device__ __forceinline__ void gld_lds16(const void* g, void* l) {
    __builtin_amdgcn_global_load_lds(
        (const __attribute__((address_space(1))) unsigned int*)g,
        (__attribute__((address_space(3))) unsigned int*)l, 16, 0, 0);
}

__device__ __forceinline__ ushort_t f2bf(float v) {
    __hip_bfloat16 h = __float2bfloat16(v);
    return *(ushort_t*)&h;
}

// ---------------------------------------------------------------------------
// Convert fp32 row-major [mtiles*16][2048] -> bf16 A-fragment layout
// Af[mt][sk][lane][8]: element = src[mt*16 + (lane&15)][sk*32 + (lane>>4)*8 + j]
// ---------------------------------------------------------------------------
__global__ void conv_frag(const float* __restrict__ src, ushort_t* __restrict__ dst) {
    int id = blockIdx.x * 256 + threadIdx.x;     // one thread per 8 elements
    int l  = id & 63;
    int sk = (id >> 6) & 63;
    int mt = id >> 12;
    const float* s = src + (size_t)(mt * 16 + (l & 15)) * DD + sk * 32 + ((l >> 4) * 8);
    float4 a = *(const float4*)s;
    float4 b = *(const float4*)(s + 4);
    u16x8 r;
    r[0] = f2bf(a.x); r[1] = f2bf(a.y); r[2] = f2bf(a.z); r[3] = f2bf(a.w);
    r[4] = f2bf(b.x); r[5] = f2bf(b.y); r[6] = f2bf(b.z); r[7] = f2bf(b.w);
    *(u16x8*)(dst + (size_t)id * 8) = r;
}

// ---------------------------------------------------------------------------
// Transpose fp32 W[k][n] -> bf16 Wt[n][k]
// ---------------------------------------------------------------------------
__global__ void conv_wt(const float* __restrict__ W, ushort_t* __restrict__ Wt) {
    int id = blockIdx.x * 256 + threadIdx.x;     // 2048*256 threads
    int n  = id & (DD - 1);
    int k8 = id >> 11;                           // 0..255
    u16x8 r;
#pragma unroll
    for (int j = 0; j < 8; ++j)
        r[j] = f2bf(W[(size_t)(k8 * 8 + j) * DD + n]);
    *(u16x8*)(Wt + (size_t)n * DD + k8 * 8) = r;
}

// ---------------------------------------------------------------------------
// m97-style GEMM: C[M x 2048] = Af @ Bt^T
//   Af: bf16 A-fragment layout [M/16][64][64][8]
//   Bt: bf16 [n][k] (transposed weights)
//   C : fp32 row-major
// Block: 256 threads (4 waves, 2x2), 128x128 tile, BK=32, global_load_lds(16B)
// Grid: (M/128, 16); blockIdx.x = M dim so consecutive blocks share the B panel
// ---------------------------------------------------------------------------
__global__ __launch_bounds__(256) void gemm_frag(
    const ushort_t* __restrict__ Af, const ushort_t* __restrict__ Bt,
    float* __restrict__ C) {
    __shared__ ushort_t lA[8 * 64 * 8];   // [row tile i][lane][8]  8KB
    __shared__ ushort_t lB[8 * 64 * 8];   // [col tile jt][lane][8] 8KB
    int tid = threadIdx.x;
    int w = tid >> 6, l = tid & 63;
    int wm = w >> 1, wn = w & 1;
    int quad = l >> 4, col = l & 15;
    int mt0 = blockIdx.x * 8;
    int n0  = blockIdx.y * 128;

    f32x4 acc[4][4] = {};

    for (int sk = 0; sk < KT; ++sk) {
        __syncthreads();   // protect LDS from previous iteration's reads
#pragma unroll
        for (int q = 0; q < 2; ++q) {
            int i = w * 2 + q;
            const ushort_t* ga = Af + ((size_t)((mt0 + i) * 64 + sk) * 64 + l) * 8;
            gld_lds16(ga, &lA[i * 512]);
            int jt = i;
            const ushort_t* gb = Bt + (size_t)(n0 + jt * 16 + col) * DD + sk * 32 + quad * 8;
            gld_lds16(gb, &lB[jt * 512]);
        }
        __syncthreads();   // drains vmcnt before barrier
        bf16x8 af[4], bf[4];
#pragma unroll
        for (int i = 0; i < 4; ++i) af[i] = *(const bf16x8*)&lA[((wm * 4 + i) * 64 + l) * 8];
#pragma unroll
        for (int j = 0; j < 4; ++j) bf[j] = *(const bf16x8*)&lB[((wn * 4 + j) * 64 + l) * 8];
#pragma unroll
        for (int i = 0; i < 4; ++i)
#pragma unroll
            for (int j = 0; j < 4; ++j)
                acc[i][j] = __builtin_amdgcn_mfma_f32_16x16x32_bf16(af[i], bf[j], acc[i][j], 0, 0, 0);
    }

#pragma unroll
    for (int i = 0; i < 4; ++i)
#pragma unroll
        for (int j = 0; j < 4; ++j) {
            int rg0 = (mt0 + wm * 4 + i) * 16 + quad * 4;
            int cg  = n0 + (wn * 4 + j) * 16 + col;
#pragma unroll
            for (int r = 0; r < 4; ++r)
                C[(size_t)(rg0 + r) * DD + cg] = acc[i][j][r];
        }
}

// ---------------------------------------------------------------------------
// Persistent recurrence kernel: 64 blocks x 256 threads, block owns 32 columns.
// Wh slice lives in registers (32 bf16x8 frags per wave). Grid barrier per step
// via monotone device-scope counter. h_t written in A-fragment layout (bf16).
// ---------------------------------------------------------------------------
__global__ __launch_bounds__(256, 1) void rnn_steps(
    const ushort_t* __restrict__ Wht,   // bf16 [n][k]
    ushort_t* __restrict__ Hf,          // (TT+1) slots of A-fragment h
    const float* __restrict__ A32,      // fp32 [TT*16][2048] = x@Wx
    float* __restrict__ hfin,           // d_out[0:32768] h_final fp32
    unsigned* __restrict__ cnt) {
    __shared__ float scr[2048];         // [wave][jt][lane][4] partial sums, 8KB
    int tid = threadIdx.x;
    int w = tid >> 6, l = tid & 63;
    int quad = l >> 4, col = l & 15;
    int c0 = blockIdx.x * 32;

    // Preload this wave's Wh fragments into registers: k quarter = [w*512, w*512+512)
    bf16x8 wh[16][2];
#pragma unroll
    for (int s = 0; s < 16; ++s) {
        int sk = w * 16 + s;
#pragma unroll
        for (int jt = 0; jt < 2; ++jt)
            wh[s][jt] = *(const bf16x8*)(Wht + (size_t)(c0 + jt * 16 + col) * DD + sk * 32 + quad * 8);
    }

    for (int t = 1; t <= TT; ++t) {
        const ushort_t* hprev = Hf + (size_t)(t - 1) * HF_SLOT;
        f32x4 acc0 = {0.f, 0.f, 0.f, 0.f};
        f32x4 acc1 = {0.f, 0.f, 0.f, 0.f};
#pragma unroll
        for (int s = 0; s < 16; ++s) {
            int sk = w * 16 + s;
            bf16x8 a = *(const bf16x8*)(hprev + (size_t)(sk * 64 + l) * 8);
            acc0 = __builtin_amdgcn_mfma_f32_16x16x32_bf16(a, wh[s][0], acc0, 0, 0, 0);
            acc1 = __builtin_amdgcn_mfma_f32_16x16x32_bf16(a, wh[s][1], acc1, 0, 0, 0);
        }
        *(f32x4*)&scr[((w * 2 + 0) * 64 + l) * 4] = acc0;
        *(f32x4*)&scr[((w * 2 + 1) * 64 + l) * 4] = acc1;
        __syncthreads();

        if (w < 2) {   // waves 0,1 finish the 2 column tiles
            int jt = w;
            f32x4 p0 = *(f32x4*)&scr[((0 * 2 + jt) * 64 + l) * 4];
            f32x4 p1 = *(f32x4*)&scr[((1 * 2 + jt) * 64 + l) * 4];
            f32x4 p2 = *(f32x4*)&scr[((2 * 2 + jt) * 64 + l) * 4];
            f32x4 p3 = *(f32x4*)&scr[((3 * 2 + jt) * 64 + l) * 4];
            int kcol = c0 + jt * 16 + col;
            int ssk = kcol >> 5, q2 = (kcol >> 3) & 3, jj = kcol & 7;
            ushort_t* hdst = Hf + (size_t)t * HF_SLOT;
#pragma unroll
            for (int r = 0; r < 4; ++r) {
                int m = quad * 4 + r;                       // C/D layout: row=(l>>4)*4+r
                float sum = p0[r] + p1[r] + p2[r] + p3[r];
                float aval = A32[(size_t)((t - 1) * 16 + m) * DD + kcol];
                float x = sum + aval;
                float e2 = __expf(-2.f * fabsf(x));
                float th = (1.f - e2) / (1.f + e2);
                th = copysignf(th, x);
                hdst[(size_t)(ssk * 64 + (q2 * 16 + m)) * 8 + jj] = f2bf(th);
                if (t == TT) hfin[(size_t)m * DD + kcol] = th;
            }
        }
        __syncthreads();   // all Hf[t] writes issued before the fence
        if (tid == 0) {
            __threadfence();                                // release: flush L2 -> LLC
            __hip_atomic_fetch_add(cnt, 1u, __ATOMIC_RELAXED, __HIP_MEMORY_SCOPE_AGENT);
            unsigned target = (unsigned)(NBLK * t);
            while (__hip_atomic_load(cnt, __ATOMIC_RELAXED, __HIP_MEMORY_SCOPE_AGENT) < target)
                __builtin_amdgcn_s_sleep(1);
            __threadfence();                                // acquire: invalidate L1/L2
        }
        __syncthreads();
    }
}

// ---------------------------------------------------------------------------
extern "C" void kernel_launch(void* const* d_in, const int* in_sizes, int n_in,
                              void* d_out, int out_size, void* d_ws, size_t ws_size,
                              hipStream_t stream) {
    const float* h0 = (const float*)d_in[0];
    const float* x  = (const float*)d_in[1];
    const float* Wx = (const float*)d_in[2];
    const float* Wh = (const float*)d_in[3];
    const float* Wo = (const float*)d_in[4];
    float* out = (float*)d_out;

    char* ws = (char*)d_ws;
    unsigned* cnt = (unsigned*)ws;                               // 256 B
    ushort_t* Hf  = (ushort_t*)(ws + 256);                       // 513 slots * 64KB
    ushort_t* Xf  = Hf + HF_SLOT;                                // alias Hf slots 1..512 (dead after phase 1)
    size_t hf_bytes = (size_t)(TT + 1) * HF_SLOT * 2;
    ushort_t* Wxt = (ushort_t*)(ws + 256 + hf_bytes);
    ushort_t* Wht = Wxt + (size_t)DD * DD;
    ushort_t* Wot = Wht + (size_t)DD * DD;
    float* A32 = out + HF_SLOT;                                  // ys region, dead until phase 3

    hipMemsetAsync(d_ws, 0, 256, stream);

    // fp32 -> bf16 layout conversions
    conv_frag<<<8192, 256, 0, stream>>>(x, Xf);                  // X fragments
    conv_frag<<<16, 256, 0, stream>>>(h0, Hf);                   // h0 -> slot 0
    conv_wt<<<2048, 256, 0, stream>>>(Wx, Wxt);
    conv_wt<<<2048, 256, 0, stream>>>(Wh, Wht);
    conv_wt<<<2048, 256, 0, stream>>>(Wo, Wot);

    // Phase 1: A32 = X @ Wx   (fp32 out, lives in d_out's ys region)
    gemm_frag<<<dim3(64, 16), 256, 0, stream>>>(Xf, Wxt, A32);

    // Phase 2: sequential recurrence, h_t fragments into Hf slots 1..512
    rnn_steps<<<NBLK, 256, 0, stream>>>(Wht, Hf, A32, out, cnt);

    // Phase 3: ys = H @ Wo  (overwrites A32 region with final output)
    gemm_frag<<<dim3(64, 16), 256, 0, stream>>>(Hf + HF_SLOT, Wot, out + HF_SLOT);
}

// Round 2
// 4443.744 us; speedup vs baseline: 1.2108x; 1.2108x over previous
//
#include <hip/hip_runtime.h>
#include <hip/hip_bf16.h>

// Problem constants
#define DD 2048
#define TT 512
#define NBLK 64           // recurrence workgroups
#define HF_SLOT 32768     // elements per h fragment slot (16 x 2048)
#define KT 64             // K tiles of 32 (DD/32)

typedef __attribute__((ext_vector_type(4))) float  f32x4;
typedef __attribute__((ext_vector_type(8))) short  bf16x8;
typedef __attribute__((ext_vector_type(8))) unsigned short u16x8;
typedef unsigned short ushort_t;
typedef unsigned long long u64_t;

__device__ __forceinline__ void gld_lds16(const void* g, void* l) {
    __builtin_amdgcn_global_load_lds(
        (const __attribute__((address_space(1))) unsigned int*)g,
        (__attribute__((address_space(3))) unsigned int*)l, 16, 0, 0);
}

__device__ __forceinline__ ushort_t f2bf(float v) {
    __hip_bfloat16 h = __float2bfloat16(v);
    return *(ushort_t*)&h;
}

// ---------------------------------------------------------------------------
// Convert fp32 row-major [mtiles*16][2048] -> bf16 A-fragment layout
// Af[mt][sk][lane][8]: element = src[mt*16 + (lane&15)][sk*32 + (lane>>4)*8 + j]
// ---------------------------------------------------------------------------
__global__ void conv_frag(const float* __restrict__ src, ushort_t* __restrict__ dst) {
    int id = blockIdx.x * 256 + threadIdx.x;     // one thread per 8 elements
    int l  = id & 63;
    int sk = (id >> 6) & 63;
    int mt = id >> 12;
    const float* s = src + (size_t)(mt * 16 + (l & 15)) * DD + sk * 32 + ((l >> 4) * 8);
    float4 a = *(const float4*)s;
    float4 b = *(const float4*)(s + 4);
    u16x8 r;
    r[0] = f2bf(a.x); r[1] = f2bf(a.y); r[2] = f2bf(a.z); r[3] = f2bf(a.w);
    r[4] = f2bf(b.x); r[5] = f2bf(b.y); r[6] = f2bf(b.z); r[7] = f2bf(b.w);
    *(u16x8*)(dst + (size_t)id * 8) = r;
}

// ---------------------------------------------------------------------------
// Transpose fp32 W[k][n] -> bf16 Wt[n][k]
// ---------------------------------------------------------------------------
__global__ void conv_wt(const float* __restrict__ W, ushort_t* __restrict__ Wt) {
    int id = blockIdx.x * 256 + threadIdx.x;     // 2048*256 threads
    int n  = id & (DD - 1);
    int k8 = id >> 11;                           // 0..255
    u16x8 r;
#pragma unroll
    for (int j = 0; j < 8; ++j)
        r[j] = f2bf(W[(size_t)(k8 * 8 + j) * DD + n]);
    *(u16x8*)(Wt + (size_t)n * DD + k8 * 8) = r;
}

// ---------------------------------------------------------------------------
// m97-style GEMM: C[M x 2048] = Af @ Bt^T  (unchanged from round 1)
// ---------------------------------------------------------------------------
__global__ __launch_bounds__(256) void gemm_frag(
    const ushort_t* __restrict__ Af, const ushort_t* __restrict__ Bt,
    float* __restrict__ C) {
    __shared__ ushort_t lA[8 * 64 * 8];   // 8KB
    __shared__ ushort_t lB[8 * 64 * 8];   // 8KB
    int tid = threadIdx.x;
    int w = tid >> 6, l = tid & 63;
    int wm = w >> 1, wn = w & 1;
    int quad = l >> 4, col = l & 15;
    int mt0 = blockIdx.x * 8;
    int n0  = blockIdx.y * 128;

    f32x4 acc[4][4] = {};

    for (int sk = 0; sk < KT; ++sk) {
        __syncthreads();
#pragma unroll
        for (int q = 0; q < 2; ++q) {
            int i = w * 2 + q;
            const ushort_t* ga = Af + ((size_t)((mt0 + i) * 64 + sk) * 64 + l) * 8;
            gld_lds16(ga, &lA[i * 512]);
            int jt = i;
            const ushort_t* gb = Bt + (size_t)(n0 + jt * 16 + col) * DD + sk * 32 + quad * 8;
            gld_lds16(gb, &lB[jt * 512]);
        }
        __syncthreads();
        bf16x8 af[4], bf[4];
#pragma unroll
        for (int i = 0; i < 4; ++i) af[i] = *(const bf16x8*)&lA[((wm * 4 + i) * 64 + l) * 8];
#pragma unroll
        for (int j = 0; j < 4; ++j) bf[j] = *(const bf16x8*)&lB[((wn * 4 + j) * 64 + l) * 8];
#pragma unroll
        for (int i = 0; i < 4; ++i)
#pragma unroll
            for (int j = 0; j < 4; ++j)
                acc[i][j] = __builtin_amdgcn_mfma_f32_16x16x32_bf16(af[i], bf[j], acc[i][j], 0, 0, 0);
    }

#pragma unroll
    for (int i = 0; i < 4; ++i)
#pragma unroll
        for (int j = 0; j < 4; ++j) {
            int rg0 = (mt0 + wm * 4 + i) * 16 + quad * 4;
            int cg  = n0 + (wn * 4 + j) * 16 + col;
#pragma unroll
            for (int r = 0; r < 4; ++r)
                C[(size_t)(rg0 + r) * DD + cg] = acc[i][j][r];
        }
}

// ---------------------------------------------------------------------------
// Recurrence: 64 blocks x 256 threads. Wh slice in LDS (128 KB, staged once).
// Per-step sync: per-block flag store (release) + coalesced 64-flag poll +
// acquire fence. h_t staged in LDS then written as 128 coalesced 8B stores.
// ---------------------------------------------------------------------------
__global__ __launch_bounds__(256, 1) void rnn_steps(
    const ushort_t* __restrict__ Wht,   // bf16 [n][k]
    ushort_t* __restrict__ Hf,          // (TT+1) slots of A-fragment h
    const float* __restrict__ A32,      // fp32 [TT*16][2048] = x@Wx
    float* __restrict__ hfin,           // d_out[0:32768] h_final fp32
    unsigned* __restrict__ flags) {     // NBLK flags, zeroed at launch
    __shared__ ushort_t lWh[4 * 16 * 2 * 512];  // 128 KB: ((w*16+s)*2+jt)*512 + l*8
    __shared__ float scr[2048];                 // 8 KB reduction scratch
    __shared__ ushort_t hstage[512];            // 1 KB h-output staging
    int tid = threadIdx.x;
    int w = tid >> 6, l = tid & 63;
    int quad = l >> 4, col = l & 15;
    int c0 = blockIdx.x * 32;
    int b = blockIdx.x;

    // Stage this block's Wh slice (2048 K x 32 N) into LDS, wave w owns K
    // quarter [w*512, w*512+512).
#pragma unroll
    for (int s = 0; s < 16; ++s) {
        int sk = w * 16 + s;
#pragma unroll
        for (int jt = 0; jt < 2; ++jt) {
            const ushort_t* gb = Wht + (size_t)(c0 + jt * 16 + col) * DD + sk * 32 + quad * 8;
            gld_lds16(gb, &lWh[((w * 16 + s) * 2 + jt) << 9]);
        }
    }
    __syncthreads();

    for (int t = 1; t <= TT; ++t) {
        // Prefetch A32 addend into the lanes that will consume it (issued
        // before the poll so HBM latency hides behind the wait).
        float av[4];
        if (w < 2) {
#pragma unroll
            for (int r = 0; r < 4; ++r)
                av[r] = A32[(size_t)((t - 1) * 16 + quad * 4 + r) * DD + c0 + w * 16 + col];
        }

        if (t > 1) {
            unsigned tgt = (unsigned)(t - 1);
            unsigned f;
            do {
                f = __hip_atomic_load(&flags[l], __ATOMIC_RELAXED, __HIP_MEMORY_SCOPE_AGENT);
            } while (!__all((int)(f >= tgt)));
            __builtin_amdgcn_fence(__ATOMIC_ACQUIRE, "agent");  // invalidate L1/L2 once
        }

        // Load h_{t-1} fragments (normal dwordx4; caches were just invalidated
        // so these pull fresh data from LLC).
        const ushort_t* hprev = Hf + (size_t)(t - 1) * HF_SLOT;
        bf16x8 hv[16];
#pragma unroll
        for (int s = 0; s < 16; ++s) {
            int sk = w * 16 + s;
            hv[s] = *(const bf16x8*)(hprev + (size_t)(sk * 64 + l) * 8);
        }

        f32x4 acc0 = {0.f, 0.f, 0.f, 0.f};
        f32x4 acc1 = {0.f, 0.f, 0.f, 0.f};
#pragma unroll
        for (int s = 0; s < 16; ++s) {
            bf16x8 w0 = *(const bf16x8*)&lWh[(((w * 16 + s) * 2 + 0) << 9) + l * 8];
            bf16x8 w1 = *(const bf16x8*)&lWh[(((w * 16 + s) * 2 + 1) << 9) + l * 8];
            acc0 = __builtin_amdgcn_mfma_f32_16x16x32_bf16(hv[s], w0, acc0, 0, 0, 0);
            acc1 = __builtin_amdgcn_mfma_f32_16x16x32_bf16(hv[s], w1, acc1, 0, 0, 0);
        }
        *(f32x4*)&scr[((w * 2 + 0) * 64 + l) * 4] = acc0;
        *(f32x4*)&scr[((w * 2 + 1) * 64 + l) * 4] = acc1;
        __syncthreads();

        if (w < 2) {   // waves 0,1 finish the 2 column tiles
            int jt = w;
            f32x4 p0 = *(f32x4*)&scr[((0 * 2 + jt) * 64 + l) * 4];
            f32x4 p1 = *(f32x4*)&scr[((1 * 2 + jt) * 64 + l) * 4];
            f32x4 p2 = *(f32x4*)&scr[((2 * 2 + jt) * 64 + l) * 4];
            f32x4 p3 = *(f32x4*)&scr[((3 * 2 + jt) * 64 + l) * 4];
            int lc = jt * 16 + col;          // 0..31 within block's column slice
            int q2 = lc >> 3, jj = lc & 7;
#pragma unroll
            for (int r = 0; r < 4; ++r) {
                int m = quad * 4 + r;        // C/D layout: row=(l>>4)*4+r
                float x = p0[r] + p1[r] + p2[r] + p3[r] + av[r];
                float e2 = __expf(-2.f * fabsf(x));
                float th = copysignf((1.f - e2) / (1.f + e2), x);
                hstage[(q2 * 16 + m) * 8 + jj] = f2bf(th);
                if (t == TT) hfin[(size_t)m * DD + c0 + lc] = th;
            }
        }
        __syncthreads();

        // Block's 512-ushort output region is contiguous in fragment layout:
        // slot base + (c0>>5)*512. Write as 128 coalesced 8B stores.
        if (tid < 128) {
            u64_t v = ((const u64_t*)hstage)[tid];
            *((u64_t*)(Hf + (size_t)t * HF_SLOT + (size_t)(c0 >> 5) * 512) + tid) = v;
        }
        __syncthreads();   // drains vmcnt in every wave before the flag

        if (tid == 0)      // release store: wbl2 flushes this XCD's dirty h lines
            __hip_atomic_store(&flags[b], (unsigned)t, __ATOMIC_RELEASE, __HIP_MEMORY_SCOPE_AGENT);
    }
}

// ---------------------------------------------------------------------------
extern "C" void kernel_launch(void* const* d_in, const int* in_sizes, int n_in,
                              void* d_out, int out_size, void* d_ws, size_t ws_size,
                              hipStream_t stream) {
    const float* h0 = (const float*)d_in[0];
    const float* x  = (const float*)d_in[1];
    const float* Wx = (const float*)d_in[2];
    const float* Wh = (const float*)d_in[3];
    const float* Wo = (const float*)d_in[4];
    float* out = (float*)d_out;

    char* ws = (char*)d_ws;
    unsigned* flags = (unsigned*)ws;                             // 256 B (64 flags)
    ushort_t* Hf  = (ushort_t*)(ws + 256);                       // 513 slots * 64KB
    ushort_t* Xf  = Hf + HF_SLOT;                                // alias slots 1..512 (dead after phase 1)
    size_t hf_bytes = (size_t)(TT + 1) * HF_SLOT * 2;
    ushort_t* Wxt = (ushort_t*)(ws + 256 + hf_bytes);
    ushort_t* Wht = Wxt + (size_t)DD * DD;
    ushort_t* Wot = Wht + (size_t)DD * DD;
    float* A32 = out + HF_SLOT;                                  // ys region, dead until phase 3

    hipMemsetAsync(d_ws, 0, 256, stream);

    // fp32 -> bf16 layout conversions
    conv_frag<<<8192, 256, 0, stream>>>(x, Xf);                  // X fragments
    conv_frag<<<16, 256, 0, stream>>>(h0, Hf);                   // h0 -> slot 0
    conv_wt<<<2048, 256, 0, stream>>>(Wx, Wxt);
    conv_wt<<<2048, 256, 0, stream>>>(Wh, Wht);
    conv_wt<<<2048, 256, 0, stream>>>(Wo, Wot);

    // Phase 1: A32 = X @ Wx   (fp32 out, lives in d_out's ys region)
    gemm_frag<<<dim3(64, 16), 256, 0, stream>>>(Xf, Wxt, A32);

    // Phase 2: sequential recurrence, h_t fragments into Hf slots 1..512
    rnn_steps<<<NBLK, 256, 0, stream>>>(Wht, Hf, A32, out, flags);

    // Phase 3: ys = H @ Wo  (overwrites A32 region with final output)
    gemm_frag<<<dim3(64, 16), 256, 0, stream>>>(Hf + HF_SLOT, Wot, out + HF_SLOT);
}

// Round 3
// 3150.182 us; speedup vs baseline: 1.7080x; 1.4106x over previous
//
#include <hip/hip_runtime.h>
#include <hip/hip_bf16.h>

// Problem constants
#define DD 2048
#define TT 512
#define NBLK 64           // recurrence workgroups
#define HF_SLOT 32768     // elements per h fragment slot (16 x 2048)
#define KT 64             // K tiles of 32 (DD/32)

typedef __attribute__((ext_vector_type(4))) float  f32x4;
typedef __attribute__((ext_vector_type(8))) short  bf16x8;
typedef __attribute__((ext_vector_type(8))) unsigned short u16x8;
typedef unsigned short ushort_t;
typedef unsigned long long u64_t;

__device__ __forceinline__ void gld_lds16(const void* g, void* l) {
    __builtin_amdgcn_global_load_lds(
        (const __attribute__((address_space(1))) unsigned int*)g,
        (__attribute__((address_space(3))) unsigned int*)l, 16, 0, 0);
}

__device__ __forceinline__ ushort_t f2bf(float v) {
    __hip_bfloat16 h = __float2bfloat16(v);
    return *(ushort_t*)&h;
}

// LLC-coherent (agent-scope, sc0+sc1) 8B load/store — no wbl2/inv needed.
__device__ __forceinline__ u64_t llc_load(const u64_t* p) {
    return __hip_atomic_load(p, __ATOMIC_RELAXED, __HIP_MEMORY_SCOPE_AGENT);
}
__device__ __forceinline__ void llc_store(u64_t* p, u64_t v) {
    __hip_atomic_store(p, v, __ATOMIC_RELAXED, __HIP_MEMORY_SCOPE_AGENT);
}

// ---------------------------------------------------------------------------
// Convert fp32 row-major [mtiles*16][2048] -> bf16 A-fragment layout
// Af[mt][sk][lane][8]: element = src[mt*16 + (lane&15)][sk*32 + (lane>>4)*8 + j]
// ---------------------------------------------------------------------------
__global__ void conv_frag(const float* __restrict__ src, ushort_t* __restrict__ dst) {
    int id = blockIdx.x * 256 + threadIdx.x;     // one thread per 8 elements
    int l  = id & 63;
    int sk = (id >> 6) & 63;
    int mt = id >> 12;
    const float* s = src + (size_t)(mt * 16 + (l & 15)) * DD + sk * 32 + ((l >> 4) * 8);
    float4 a = *(const float4*)s;
    float4 b = *(const float4*)(s + 4);
    u16x8 r;
    r[0] = f2bf(a.x); r[1] = f2bf(a.y); r[2] = f2bf(a.z); r[3] = f2bf(a.w);
    r[4] = f2bf(b.x); r[5] = f2bf(b.y); r[6] = f2bf(b.z); r[7] = f2bf(b.w);
    *(u16x8*)(dst + (size_t)id * 8) = r;
}

// ---------------------------------------------------------------------------
// Transpose fp32 W[k][n] -> bf16 Wt[n][k]
// ---------------------------------------------------------------------------
__global__ void conv_wt(const float* __restrict__ W, ushort_t* __restrict__ Wt) {
    int id = blockIdx.x * 256 + threadIdx.x;     // 2048*256 threads
    int n  = id & (DD - 1);
    int k8 = id >> 11;                           // 0..255
    u16x8 r;
#pragma unroll
    for (int j = 0; j < 8; ++j)
        r[j] = f2bf(W[(size_t)(k8 * 8 + j) * DD + n]);
    *(u16x8*)(Wt + (size_t)n * DD + k8 * 8) = r;
}

// ---------------------------------------------------------------------------
// m97-style GEMM: C[M x 2048] = Af @ Bt^T  (unchanged)
// ---------------------------------------------------------------------------
__global__ __launch_bounds__(256) void gemm_frag(
    const ushort_t* __restrict__ Af, const ushort_t* __restrict__ Bt,
    float* __restrict__ C) {
    __shared__ ushort_t lA[8 * 64 * 8];   // 8KB
    __shared__ ushort_t lB[8 * 64 * 8];   // 8KB
    int tid = threadIdx.x;
    int w = tid >> 6, l = tid & 63;
    int wm = w >> 1, wn = w & 1;
    int quad = l >> 4, col = l & 15;
    int mt0 = blockIdx.x * 8;
    int n0  = blockIdx.y * 128;

    f32x4 acc[4][4] = {};

    for (int sk = 0; sk < KT; ++sk) {
        __syncthreads();
#pragma unroll
        for (int q = 0; q < 2; ++q) {
            int i = w * 2 + q;
            const ushort_t* ga = Af + ((size_t)((mt0 + i) * 64 + sk) * 64 + l) * 8;
            gld_lds16(ga, &lA[i * 512]);
            int jt = i;
            const ushort_t* gb = Bt + (size_t)(n0 + jt * 16 + col) * DD + sk * 32 + quad * 8;
            gld_lds16(gb, &lB[jt * 512]);
        }
        __syncthreads();
        bf16x8 af[4], bf[4];
#pragma unroll
        for (int i = 0; i < 4; ++i) af[i] = *(const bf16x8*)&lA[((wm * 4 + i) * 64 + l) * 8];
#pragma unroll
        for (int j = 0; j < 4; ++j) bf[j] = *(const bf16x8*)&lB[((wn * 4 + j) * 64 + l) * 8];
#pragma unroll
        for (int i = 0; i < 4; ++i)
#pragma unroll
            for (int j = 0; j < 4; ++j)
                acc[i][j] = __builtin_amdgcn_mfma_f32_16x16x32_bf16(af[i], bf[j], acc[i][j], 0, 0, 0);
    }

#pragma unroll
    for (int i = 0; i < 4; ++i)
#pragma unroll
        for (int j = 0; j < 4; ++j) {
            int rg0 = (mt0 + wm * 4 + i) * 16 + quad * 4;
            int cg  = n0 + (wn * 4 + j) * 16 + col;
#pragma unroll
            for (int r = 0; r < 4; ++r)
                C[(size_t)(rg0 + r) * DD + cg] = acc[i][j][r];
        }
}

// ---------------------------------------------------------------------------
// Recurrence: 64 blocks x 256 threads. Wh slice in LDS (128 KB, staged once).
// All cross-block h/flag traffic via agent-scope relaxed atomics (sc0+sc1,
// LLC-coherent) — NO release/acquire fences, so no buffer_wbl2 / buffer_inv
// in the per-step critical path.
// ---------------------------------------------------------------------------
__global__ __launch_bounds__(256, 1) void rnn_steps(
    const ushort_t* __restrict__ Wht,   // bf16 [n][k]
    ushort_t* __restrict__ Hf,          // (TT+1) slots of A-fragment h
    const float* __restrict__ A32,      // fp32 [TT*16][2048] = x@Wx
    float* __restrict__ hfin,           // d_out[0:32768] h_final fp32
    unsigned* __restrict__ flags) {     // NBLK flags, zeroed at launch
    __shared__ ushort_t lWh[4 * 16 * 2 * 512];  // 128 KB
    __shared__ float scr[2048];                 // 8 KB reduction scratch
    __shared__ ushort_t hstage[512];            // 1 KB h-output staging
    int tid = threadIdx.x;
    int w = tid >> 6, l = tid & 63;
    int quad = l >> 4, col = l & 15;
    int c0 = blockIdx.x * 32;
    int b = blockIdx.x;

    // Stage this block's Wh slice (2048 K x 32 N) into LDS.
#pragma unroll
    for (int s = 0; s < 16; ++s) {
        int sk = w * 16 + s;
#pragma unroll
        for (int jt = 0; jt < 2; ++jt) {
            const ushort_t* gb = Wht + (size_t)(c0 + jt * 16 + col) * DD + sk * 32 + quad * 8;
            gld_lds16(gb, &lWh[((w * 16 + s) * 2 + jt) << 9]);
        }
    }
    __syncthreads();

    for (int t = 1; t <= TT; ++t) {
        // Prefetch A32 addend (normal cached loads; A32 written by a prior
        // kernel, never re-written — no coherence hazard). Issued before the
        // poll so HBM latency hides behind the wait.
        float av[4];
        if (w < 2) {
#pragma unroll
            for (int r = 0; r < 4; ++r)
                av[r] = A32[(size_t)((t - 1) * 16 + quad * 4 + r) * DD + c0 + w * 16 + col];
        }

        if (t > 1) {
            unsigned tgt = (unsigned)(t - 1);
            unsigned f;
            do {
                f = __hip_atomic_load(&flags[l], __ATOMIC_RELAXED, __HIP_MEMORY_SCOPE_AGENT);
            } while (!__all((int)(f >= tgt)));
        }

        // Load h_{t-1} fragments straight from LLC (agent-scope loads bypass
        // the possibly-stale L1/L2). t=1 slot was published by a prior kernel.
        const ushort_t* hprev = Hf + (size_t)(t - 1) * HF_SLOT;
        bf16x8 hv[16];
#pragma unroll
        for (int s = 0; s < 16; ++s) {
            int sk = w * 16 + s;
            const u64_t* p = (const u64_t*)(hprev + (size_t)(sk * 64 + l) * 8);
            union { u64_t q[2]; bf16x8 v; } u;
            u.q[0] = llc_load(p);
            u.q[1] = llc_load(p + 1);
            hv[s] = u.v;
        }

        f32x4 acc0 = {0.f, 0.f, 0.f, 0.f};
        f32x4 acc1 = {0.f, 0.f, 0.f, 0.f};
#pragma unroll
        for (int s = 0; s < 16; ++s) {
            bf16x8 w0 = *(const bf16x8*)&lWh[(((w * 16 + s) * 2 + 0) << 9) + l * 8];
            bf16x8 w1 = *(const bf16x8*)&lWh[(((w * 16 + s) * 2 + 1) << 9) + l * 8];
            acc0 = __builtin_amdgcn_mfma_f32_16x16x32_bf16(hv[s], w0, acc0, 0, 0, 0);
            acc1 = __builtin_amdgcn_mfma_f32_16x16x32_bf16(hv[s], w1, acc1, 0, 0, 0);
        }
        *(f32x4*)&scr[((w * 2 + 0) * 64 + l) * 4] = acc0;
        *(f32x4*)&scr[((w * 2 + 1) * 64 + l) * 4] = acc1;
        __syncthreads();

        if (w < 2) {   // waves 0,1 finish the 2 column tiles
            int jt = w;
            f32x4 p0 = *(f32x4*)&scr[((0 * 2 + jt) * 64 + l) * 4];
            f32x4 p1 = *(f32x4*)&scr[((1 * 2 + jt) * 64 + l) * 4];
            f32x4 p2 = *(f32x4*)&scr[((2 * 2 + jt) * 64 + l) * 4];
            f32x4 p3 = *(f32x4*)&scr[((3 * 2 + jt) * 64 + l) * 4];
            int lc = jt * 16 + col;          // 0..31 within block's column slice
            int q2 = lc >> 3, jj = lc & 7;
#pragma unroll
            for (int r = 0; r < 4; ++r) {
                int m = quad * 4 + r;        // C/D layout: row=(l>>4)*4+r
                float x = p0[r] + p1[r] + p2[r] + p3[r] + av[r];
                float e2 = __expf(-2.f * fabsf(x));
                float th = copysignf((1.f - e2) / (1.f + e2), x);
                hstage[(q2 * 16 + m) * 8 + jj] = f2bf(th);
                if (t == TT) hfin[(size_t)m * DD + c0 + lc] = th;
            }
        }
        __syncthreads();

        // Wave 0 alone publishes the block's 1 KB h slice (contiguous in
        // fragment layout) as LLC-coherent 8B stores, drains, then sets the
        // flag. Other waves are already free to start polling step t+1 —
        // they can't pass the poll until this flag lands.
        if (w == 0) {
            u64_t* dst = (u64_t*)(Hf + (size_t)t * HF_SLOT + (size_t)(c0 >> 5) * 512);
            const u64_t* s = (const u64_t*)hstage;
            llc_store(dst + l,      s[l]);
            llc_store(dst + 64 + l, s[64 + l]);
            __builtin_amdgcn_s_waitcnt(0);   // stores acked at LLC
            if (l == 0)
                __hip_atomic_store(&flags[b], (unsigned)t, __ATOMIC_RELAXED, __HIP_MEMORY_SCOPE_AGENT);
        }
    }
}

// ---------------------------------------------------------------------------
extern "C" void kernel_launch(void* const* d_in, const int* in_sizes, int n_in,
                              void* d_out, int out_size, void* d_ws, size_t ws_size,
                              hipStream_t stream) {
    const float* h0 = (const float*)d_in[0];
    const float* x  = (const float*)d_in[1];
    const float* Wx = (const float*)d_in[2];
    const float* Wh = (const float*)d_in[3];
    const float* Wo = (const float*)d_in[4];
    float* out = (float*)d_out;

    char* ws = (char*)d_ws;
    unsigned* flags = (unsigned*)ws;                             // 256 B (64 flags)
    ushort_t* Hf  = (ushort_t*)(ws + 256);                       // 513 slots * 64KB
    ushort_t* Xf  = Hf + HF_SLOT;                                // alias slots 1..512 (dead after phase 1)
    size_t hf_bytes = (size_t)(TT + 1) * HF_SLOT * 2;
    ushort_t* Wxt = (ushort_t*)(ws + 256 + hf_bytes);
    ushort_t* Wht = Wxt + (size_t)DD * DD;
    ushort_t* Wot = Wht + (size_t)DD * DD;
    float* A32 = out + HF_SLOT;                                  // ys region, dead until phase 3

    hipMemsetAsync(d_ws, 0, 256, stream);

    // fp32 -> bf16 layout conversions
    conv_frag<<<8192, 256, 0, stream>>>(x, Xf);                  // X fragments
    conv_frag<<<16, 256, 0, stream>>>(h0, Hf);                   // h0 -> slot 0
    conv_wt<<<2048, 256, 0, stream>>>(Wx, Wxt);
    conv_wt<<<2048, 256, 0, stream>>>(Wh, Wht);
    conv_wt<<<2048, 256, 0, stream>>>(Wo, Wot);

    // Phase 1: A32 = X @ Wx   (fp32 out, lives in d_out's ys region)
    gemm_frag<<<dim3(64, 16), 256, 0, stream>>>(Xf, Wxt, A32);

    // Phase 2: sequential recurrence, h_t fragments into Hf slots 1..512
    rnn_steps<<<NBLK, 256, 0, stream>>>(Wht, Hf, A32, out, flags);

    // Phase 3: ys = H @ Wo  (overwrites A32 region with final output)
    gemm_frag<<<dim3(64, 16), 256, 0, stream>>>(Hf + HF_SLOT, Wot, out + HF_SLOT);
}

// Round 4
// 1912.439 us; speedup vs baseline: 2.8135x; 1.6472x over previous
//
#include <hip/hip_runtime.h>
#include <hip/hip_bf16.h>

// Problem constants
#define DD 2048
#define TT 512
#define NBLK 64           // recurrence workgroups (plus NBLK y-consumer workgroups)
#define HF_SLOT 32768     // elements per h fragment slot (16 x 2048)
#define KT 64             // K tiles of 32 (DD/32)
#define FSTRIDE 16        // dwords between flags (64 B -> one LLC line each)

typedef __attribute__((ext_vector_type(4))) float  f32x4;
typedef __attribute__((ext_vector_type(8))) short  bf16x8;
typedef __attribute__((ext_vector_type(8))) unsigned short u16x8;
typedef unsigned short ushort_t;
typedef unsigned long long u64_t;

__device__ __forceinline__ void gld_lds16(const void* g, void* l) {
    __builtin_amdgcn_global_load_lds(
        (const __attribute__((address_space(1))) unsigned int*)g,
        (__attribute__((address_space(3))) unsigned int*)l, 16, 0, 0);
}

__device__ __forceinline__ ushort_t f2bf(float v) {
    __hip_bfloat16 h = __float2bfloat16(v);
    return *(ushort_t*)&h;
}

// LLC-coherent (agent-scope, relaxed) accessors — no wbl2/inv emitted.
__device__ __forceinline__ u64_t llc_load64(const u64_t* p) {
    return __hip_atomic_load(p, __ATOMIC_RELAXED, __HIP_MEMORY_SCOPE_AGENT);
}
__device__ __forceinline__ void llc_store64(u64_t* p, u64_t v) {
    __hip_atomic_store(p, v, __ATOMIC_RELAXED, __HIP_MEMORY_SCOPE_AGENT);
}
__device__ __forceinline__ unsigned llc_load32(const unsigned* p) {
    return __hip_atomic_load(p, __ATOMIC_RELAXED, __HIP_MEMORY_SCOPE_AGENT);
}
__device__ __forceinline__ float llc_loadf(const float* p) {
    return __hip_atomic_load(p, __ATOMIC_RELAXED, __HIP_MEMORY_SCOPE_AGENT);
}

// ---------------------------------------------------------------------------
// Convert fp32 row-major [mtiles*16][2048] -> bf16 A-fragment layout
// ---------------------------------------------------------------------------
__global__ void conv_frag(const float* __restrict__ src, ushort_t* __restrict__ dst) {
    int id = blockIdx.x * 256 + threadIdx.x;     // one thread per 8 elements
    int l  = id & 63;
    int sk = (id >> 6) & 63;
    int mt = id >> 12;
    const float* s = src + (size_t)(mt * 16 + (l & 15)) * DD + sk * 32 + ((l >> 4) * 8);
    float4 a = *(const float4*)s;
    float4 b = *(const float4*)(s + 4);
    u16x8 r;
    r[0] = f2bf(a.x); r[1] = f2bf(a.y); r[2] = f2bf(a.z); r[3] = f2bf(a.w);
    r[4] = f2bf(b.x); r[5] = f2bf(b.y); r[6] = f2bf(b.z); r[7] = f2bf(b.w);
    *(u16x8*)(dst + (size_t)id * 8) = r;
}

// ---------------------------------------------------------------------------
// Transpose fp32 W[k][n] -> bf16 Wt[n][k]
// ---------------------------------------------------------------------------
__global__ void conv_wt(const float* __restrict__ W, ushort_t* __restrict__ Wt) {
    int id = blockIdx.x * 256 + threadIdx.x;
    int n  = id & (DD - 1);
    int k8 = id >> 11;
    u16x8 r;
#pragma unroll
    for (int j = 0; j < 8; ++j)
        r[j] = f2bf(W[(size_t)(k8 * 8 + j) * DD + n]);
    *(u16x8*)(Wt + (size_t)n * DD + k8 * 8) = r;
}

// ---------------------------------------------------------------------------
// m97-style GEMM: C[M x 2048] = Af @ Bt^T  (phase 1 only now)
// ---------------------------------------------------------------------------
__global__ __launch_bounds__(256) void gemm_frag(
    const ushort_t* __restrict__ Af, const ushort_t* __restrict__ Bt,
    float* __restrict__ C) {
    __shared__ ushort_t lA[8 * 64 * 8];
    __shared__ ushort_t lB[8 * 64 * 8];
    int tid = threadIdx.x;
    int w = tid >> 6, l = tid & 63;
    int wm = w >> 1, wn = w & 1;
    int quad = l >> 4, col = l & 15;
    int mt0 = blockIdx.x * 8;
    int n0  = blockIdx.y * 128;

    f32x4 acc[4][4] = {};

    for (int sk = 0; sk < KT; ++sk) {
        __syncthreads();
#pragma unroll
        for (int q = 0; q < 2; ++q) {
            int i = w * 2 + q;
            const ushort_t* ga = Af + ((size_t)((mt0 + i) * 64 + sk) * 64 + l) * 8;
            gld_lds16(ga, &lA[i * 512]);
            int jt = i;
            const ushort_t* gb = Bt + (size_t)(n0 + jt * 16 + col) * DD + sk * 32 + quad * 8;
            gld_lds16(gb, &lB[jt * 512]);
        }
        __syncthreads();
        bf16x8 af[4], bf[4];
#pragma unroll
        for (int i = 0; i < 4; ++i) af[i] = *(const bf16x8*)&lA[((wm * 4 + i) * 64 + l) * 8];
#pragma unroll
        for (int j = 0; j < 4; ++j) bf[j] = *(const bf16x8*)&lB[((wn * 4 + j) * 64 + l) * 8];
#pragma unroll
        for (int i = 0; i < 4; ++i)
#pragma unroll
            for (int j = 0; j < 4; ++j)
                acc[i][j] = __builtin_amdgcn_mfma_f32_16x16x32_bf16(af[i], bf[j], acc[i][j], 0, 0, 0);
    }

#pragma unroll
    for (int i = 0; i < 4; ++i)
#pragma unroll
        for (int j = 0; j < 4; ++j) {
            int rg0 = (mt0 + wm * 4 + i) * 16 + quad * 4;
            int cg  = n0 + (wn * 4 + j) * 16 + col;
#pragma unroll
            for (int r = 0; r < 4; ++r)
                C[(size_t)(rg0 + r) * DD + cg] = acc[i][j][r];
        }
}

// ---------------------------------------------------------------------------
// Fused recurrence + y-GEMM consumers. 128 blocks x 256 threads.
//   blocks 0..63   : recurrence, column slice 32*b, publish h_t + flag
//   blocks 64..127 : y = h_t @ Wo slice, consume flags, write ys fp32
// Per-step sync: single-wave (w==3) poll of 64 padded flags + __syncthreads.
// All cross-block data via agent-scope relaxed atomics (LLC-coherent).
// ---------------------------------------------------------------------------
__global__ __launch_bounds__(256, 1) void rnn_fused(
    const ushort_t* __restrict__ Wht,   // bf16 [n][k]
    const ushort_t* __restrict__ Wot,   // bf16 [n][k]
    ushort_t* __restrict__ Hf,          // (TT+1) slots of A-fragment h
    const float* __restrict__ A32,      // fp32 [TT*16][2048] = x@Wx (aliases ys!)
    float* __restrict__ out,            // [0:HF_SLOT) h_final, then ys
    unsigned* __restrict__ flags) {     // NBLK flags, 64B stride, zeroed
    __shared__ ushort_t lW[4 * 16 * 2 * 512];   // 128 KB (Wh or Wo slice)
    __shared__ float scr[2048];                 // 8 KB reduction scratch
    __shared__ ushort_t hstage[512];            // 1 KB h-output staging (rnn only)
    int tid = threadIdx.x;
    int w = tid >> 6, l = tid & 63;
    int quad = l >> 4, col = l & 15;
    bool is_rnn = blockIdx.x < NBLK;
    int b = is_rnn ? blockIdx.x : blockIdx.x - NBLK;
    int c0 = b * 32;
    float* ys = out + HF_SLOT;

    // Stage this block's weight slice (2048 K x 32 N) into LDS.
    const ushort_t* Wsrc = is_rnn ? Wht : Wot;
#pragma unroll
    for (int s = 0; s < 16; ++s) {
        int sk = w * 16 + s;
#pragma unroll
        for (int jt = 0; jt < 2; ++jt) {
            const ushort_t* gb = Wsrc + (size_t)(c0 + jt * 16 + col) * DD + sk * 32 + quad * 8;
            gld_lds16(gb, &lW[((w * 16 + s) * 2 + jt) << 9]);
        }
    }
    __syncthreads();

    for (int t = 1; t <= TT; ++t) {
        // rnn: prefetch A32 addend before the poll (latency hidden by wait).
        // Agent-scope loads: the same addresses are later overwritten by y
        // blocks (after flags >= t), so bypass local L2.
        float av[4];
        if (is_rnn && w < 2) {
#pragma unroll
            for (int r = 0; r < 4; ++r)
                av[r] = llc_loadf(&A32[(size_t)((t - 1) * 16 + quad * 4 + r) * DD + c0 + w * 16 + col]);
        }

        // Single-wave poll, broadcast via barrier.
        // rnn waits for h_{t-1} (flags >= t-1); y waits for h_t (flags >= t).
        unsigned tgt = is_rnn ? (unsigned)(t - 1) : (unsigned)t;
        if (w == 3) {
            unsigned f;
            do {
                f = llc_load32(&flags[l * FSTRIDE]);
            } while (!__all((int)(f >= tgt)));
        }
        __syncthreads();

        // Load h fragments straight from LLC.
        const ushort_t* hsrc = Hf + (size_t)(is_rnn ? t - 1 : t) * HF_SLOT;
        bf16x8 hv[16];
#pragma unroll
        for (int s = 0; s < 16; ++s) {
            int sk = w * 16 + s;
            const u64_t* p = (const u64_t*)(hsrc + (size_t)(sk * 64 + l) * 8);
            union { u64_t q[2]; bf16x8 v; } u;
            u.q[0] = llc_load64(p);
            u.q[1] = llc_load64(p + 1);
            hv[s] = u.v;
        }

        f32x4 acc0 = {0.f, 0.f, 0.f, 0.f};
        f32x4 acc1 = {0.f, 0.f, 0.f, 0.f};
#pragma unroll
        for (int s = 0; s < 16; ++s) {
            bf16x8 w0 = *(const bf16x8*)&lW[(((w * 16 + s) * 2 + 0) << 9) + l * 8];
            bf16x8 w1 = *(const bf16x8*)&lW[(((w * 16 + s) * 2 + 1) << 9) + l * 8];
            acc0 = __builtin_amdgcn_mfma_f32_16x16x32_bf16(hv[s], w0, acc0, 0, 0, 0);
            acc1 = __builtin_amdgcn_mfma_f32_16x16x32_bf16(hv[s], w1, acc1, 0, 0, 0);
        }
        *(f32x4*)&scr[((w * 2 + 0) * 64 + l) * 4] = acc0;
        *(f32x4*)&scr[((w * 2 + 1) * 64 + l) * 4] = acc1;
        __syncthreads();

        if (w < 2) {   // waves 0,1 finish the 2 column tiles
            int jt = w;
            f32x4 p0 = *(f32x4*)&scr[((0 * 2 + jt) * 64 + l) * 4];
            f32x4 p1 = *(f32x4*)&scr[((1 * 2 + jt) * 64 + l) * 4];
            f32x4 p2 = *(f32x4*)&scr[((2 * 2 + jt) * 64 + l) * 4];
            f32x4 p3 = *(f32x4*)&scr[((3 * 2 + jt) * 64 + l) * 4];
            int lc = jt * 16 + col;          // 0..31 within block's column slice
            if (is_rnn) {
                int q2 = lc >> 3, jj = lc & 7;
#pragma unroll
                for (int r = 0; r < 4; ++r) {
                    int m = quad * 4 + r;    // C/D layout: row=(l>>4)*4+r
                    float x = p0[r] + p1[r] + p2[r] + p3[r] + av[r];
                    float e2 = __expf(-2.f * fabsf(x));
                    float th = copysignf((1.f - e2) / (1.f + e2), x);
                    hstage[(q2 * 16 + m) * 8 + jj] = f2bf(th);
                    if (t == TT) out[(size_t)m * DD + c0 + lc] = th;
                }
            } else {
#pragma unroll
                for (int r = 0; r < 4; ++r) {
                    int m = quad * 4 + r;
                    float y = p0[r] + p1[r] + p2[r] + p3[r];
                    ys[(size_t)((t - 1) * 16 + m) * DD + c0 + lc] = y;
                }
            }
        }

        if (is_rnn) {
            __syncthreads();
            // Wave 0 publishes the block's 1 KB h slice + flag.
            if (w == 0) {
                u64_t* dst = (u64_t*)(Hf + (size_t)t * HF_SLOT + (size_t)(c0 >> 5) * 512);
                const u64_t* s = (const u64_t*)hstage;
                llc_store64(dst + l,      s[l]);
                llc_store64(dst + 64 + l, s[64 + l]);
                __builtin_amdgcn_s_waitcnt(0);   // stores acked at LLC
                if (l == 0)
                    __hip_atomic_store(&flags[b * FSTRIDE], (unsigned)t,
                                       __ATOMIC_RELAXED, __HIP_MEMORY_SCOPE_AGENT);
            }
        }
    }
}

// ---------------------------------------------------------------------------
extern "C" void kernel_launch(void* const* d_in, const int* in_sizes, int n_in,
                              void* d_out, int out_size, void* d_ws, size_t ws_size,
                              hipStream_t stream) {
    const float* h0 = (const float*)d_in[0];
    const float* x  = (const float*)d_in[1];
    const float* Wx = (const float*)d_in[2];
    const float* Wh = (const float*)d_in[3];
    const float* Wo = (const float*)d_in[4];
    float* out = (float*)d_out;

    char* ws = (char*)d_ws;
    unsigned* flags = (unsigned*)ws;                             // 4 KB (64 flags, 64B stride)
    ushort_t* Hf  = (ushort_t*)(ws + 4096);                      // 513 slots * 64KB
    ushort_t* Xf  = Hf + HF_SLOT;                                // alias slots 1..512 (dead after phase 1)
    size_t hf_bytes = (size_t)(TT + 1) * HF_SLOT * 2;
    ushort_t* Wxt = (ushort_t*)(ws + 4096 + hf_bytes);
    ushort_t* Wht = Wxt + (size_t)DD * DD;
    ushort_t* Wot = Wht + (size_t)DD * DD;
    float* A32 = out + HF_SLOT;                                  // ys region; y writes trail A32 reads

    hipMemsetAsync(d_ws, 0, 4096, stream);

    // fp32 -> bf16 layout conversions
    conv_frag<<<8192, 256, 0, stream>>>(x, Xf);                  // X fragments
    conv_frag<<<16, 256, 0, stream>>>(h0, Hf);                   // h0 -> slot 0
    conv_wt<<<2048, 256, 0, stream>>>(Wx, Wxt);
    conv_wt<<<2048, 256, 0, stream>>>(Wh, Wht);
    conv_wt<<<2048, 256, 0, stream>>>(Wo, Wot);

    // Phase 1: A32 = X @ Wx   (fp32, lives in d_out's ys region)
    gemm_frag<<<dim3(64, 16), 256, 0, stream>>>(Xf, Wxt, A32);

    // Phase 2+3 fused: recurrence + streaming y = h @ Wo
    rnn_fused<<<2 * NBLK, 256, 0, stream>>>(Wht, Wot, Hf, A32, out, flags);
}